// Round 4
// baseline (672.478 us; speedup 1.0000x reference)
//
#include <hip/hip_runtime.h>
#include <hip/hip_bf16.h>

#define HH   128
#define EMB  300
#define SEQ  1024
#define BS   64
#define NG   384   // 3*H

typedef __attribute__((ext_vector_type(8))) short  bf16x8;
typedef __attribute__((ext_vector_type(4))) float  f32x4;
typedef _Float16 f16x2 __attribute__((ext_vector_type(2)));

__device__ __forceinline__ unsigned short f2bf(float f) {
    unsigned int u = __float_as_uint(f);
    unsigned int r = (u + 0x7fffu + ((u >> 16) & 1u)) >> 16;   // RNE
    return (unsigned short)r;
}
__device__ __forceinline__ float fexp(float x) { return __builtin_amdgcn_exp2f(x * 1.44269504088896f); }
__device__ __forceinline__ float fsig(float x) { return __builtin_amdgcn_rcpf(1.f + fexp(-x)); }
__device__ __forceinline__ float ftanh(float x){ return __builtin_amdgcn_rcpf(1.f + fexp(-2.f*x)) * 2.f - 1.f; }

// LDS-only barrier: drains LDS ops (cross-thread hazard) but leaves global
// loads (private register dests) in flight — avoids __syncthreads()'s
// vmcnt(0) drain that serializes the gi prefetch every step.
#define BAR_LDS() asm volatile("s_waitcnt lgkmcnt(0)\n\ts_barrier" ::: "memory")

// ---------------------------------------------------------------------------
// gi[r, j] = (sum_e X[r,e]*mask[r]*W[j,e]) + bias[j]
// ---------------------------------------------------------------------------
__global__ __launch_bounds__(256) void gi_gemm(const float* __restrict__ X,
                                               const float* __restrict__ mask,
                                               const float* __restrict__ W,
                                               const float* __restrict__ bias,
                                               float* __restrict__ out) {
    __shared__ __align__(16) unsigned short As[128 * 32];
    __shared__ __align__(16) unsigned short Bs[128 * 32];
    const int m0   = blockIdx.x * 128;
    const int n0   = blockIdx.y * 128;
    const int tid  = threadIdx.x;
    const int row  = tid >> 1;            // 0..127
    const int seg  = tid & 1;             // 16-col half
    const int wave = tid >> 6;
    const int lane = tid & 63;
    const int wr   = wave >> 1, wc = wave & 1;
    const int r16  = lane & 15, kg = lane >> 4;

    f32x4 acc[4][4];
    #pragma unroll
    for (int m = 0; m < 4; ++m)
        #pragma unroll
        for (int n = 0; n < 4; ++n) acc[m][n] = (f32x4){0.f,0.f,0.f,0.f};

    const float mrow = mask[m0 + row];

    for (int k0 = 0; k0 < 320; k0 += 32) {
        // ---- stage A (x * mask -> bf16) ----
        {
            const float* src = X + (size_t)(m0 + row) * EMB + k0 + seg * 16;
            unsigned short tmp[16];
            if (k0 + seg * 16 + 15 < EMB) {
                #pragma unroll
                for (int i = 0; i < 4; ++i) {
                    float4 v = ((const float4*)src)[i];
                    tmp[i*4+0] = f2bf(v.x * mrow);
                    tmp[i*4+1] = f2bf(v.y * mrow);
                    tmp[i*4+2] = f2bf(v.z * mrow);
                    tmp[i*4+3] = f2bf(v.w * mrow);
                }
            } else {
                #pragma unroll
                for (int i = 0; i < 16; ++i) {
                    int c = k0 + seg * 16 + i;
                    float v = (c < EMB) ? src[i] : 0.f;
                    tmp[i] = f2bf(v * mrow);
                }
            }
            uint4* dst = (uint4*)&As[row * 32 + seg * 16];
            dst[0] = ((const uint4*)tmp)[0];
            dst[1] = ((const uint4*)tmp)[1];
        }
        // ---- stage B (W -> bf16) ----
        {
            const float* src = W + (size_t)(n0 + row) * EMB + k0 + seg * 16;
            unsigned short tmp[16];
            if (k0 + seg * 16 + 15 < EMB) {
                #pragma unroll
                for (int i = 0; i < 4; ++i) {
                    float4 v = ((const float4*)src)[i];
                    tmp[i*4+0] = f2bf(v.x);
                    tmp[i*4+1] = f2bf(v.y);
                    tmp[i*4+2] = f2bf(v.z);
                    tmp[i*4+3] = f2bf(v.w);
                }
            } else {
                #pragma unroll
                for (int i = 0; i < 16; ++i) {
                    int c = k0 + seg * 16 + i;
                    float v = (c < EMB) ? src[i] : 0.f;
                    tmp[i] = f2bf(v);
                }
            }
            uint4* dst = (uint4*)&Bs[row * 32 + seg * 16];
            dst[0] = ((const uint4*)tmp)[0];
            dst[1] = ((const uint4*)tmp)[1];
        }
        __syncthreads();

        bf16x8 a[4], bfr[4];
        #pragma unroll
        for (int m = 0; m < 4; ++m)
            a[m] = *(const bf16x8*)&As[(wr * 64 + m * 16 + r16) * 32 + kg * 8];
        #pragma unroll
        for (int n = 0; n < 4; ++n)
            bfr[n] = *(const bf16x8*)&Bs[(wc * 64 + n * 16 + r16) * 32 + kg * 8];
        #pragma unroll
        for (int m = 0; m < 4; ++m)
            #pragma unroll
            for (int n = 0; n < 4; ++n)
                acc[m][n] = __builtin_amdgcn_mfma_f32_16x16x32_bf16(a[m], bfr[n], acc[m][n], 0, 0, 0);
        __syncthreads();
    }

    // ---- epilogue ----
    #pragma unroll
    for (int m = 0; m < 4; ++m) {
        const int rowb = m0 + wr * 64 + m * 16 + (lane >> 4) * 4;
        #pragma unroll
        for (int n = 0; n < 4; ++n) {
            const int col = n0 + wc * 64 + n * 16 + r16;
            const float bj = bias[col];
            #pragma unroll
            for (int q = 0; q < 4; ++q)
                out[(size_t)(rowb + q) * NG + col] = acc[m][n][q] + bj;
        }
    }
}

// ---------------------------------------------------------------------------
__global__ __launch_bounds__(256) void col_sum(const float* __restrict__ X,
                                               const float* __restrict__ mask,
                                               float* __restrict__ s) {
    const int b = blockIdx.x;
    const int e = blockIdx.y * 256 + threadIdx.x;
    if (e >= EMB) return;
    float acc = 0.f;
    const float* xb = X + (size_t)b * SEQ * EMB;
    const float* mb = mask + (size_t)b * SEQ;
    for (int t = 0; t < SEQ; ++t)
        acc += xb[(size_t)t * EMB + e] * mb[t];
    s[b * EMB + e] = acc;
}

// ---------------------------------------------------------------------------
// forward GRU scan, 256 threads: thread (j, half) holds W_hh[rows j,j+128,j+256]
// cols [half*64, half*64+64) as f16x2. half=1 writes partial dots to LDS;
// half=0 combines + gates. gi prefetched 4 steps ahead (static register sets);
// BAR_LDS() keeps those global loads in flight across the per-step barriers.
// ---------------------------------------------------------------------------
__global__ __launch_bounds__(256, 1) void gru_scan(const float* __restrict__ gi,
                                                   const float* __restrict__ Whh,
                                                   const float* __restrict__ bhh,
                                                   float* __restrict__ hout) {
    const int b    = blockIdx.x;
    const int tid  = threadIdx.x;
    const int j    = tid & 127;
    const int half = tid >> 7;           // 0 or 1
    __shared__ __align__(16) _Float16 hb[2][HH];
    __shared__ float ps_r[HH], ps_z[HH], ps_n[HH];

    // ---- weights: rows j, j+HH, j+2HH, cols [half*64, half*64+64) ----
    f16x2 wr_[32], wz_[32], wn_[32];
    {
        const float2* r0 = (const float2*)(Whh + (size_t)j * HH            + half * 64);
        const float2* r1 = (const float2*)(Whh + (size_t)(j + HH) * HH     + half * 64);
        const float2* r2 = (const float2*)(Whh + (size_t)(j + 2 * HH) * HH + half * 64);
        #pragma unroll
        for (int i = 0; i < 32; ++i) {
            float2 a = r0[i], c = r1[i], d = r2[i];
            wr_[i] = (f16x2){(_Float16)a.x, (_Float16)a.y};
            wz_[i] = (f16x2){(_Float16)c.x, (_Float16)c.y};
            wn_[i] = (f16x2){(_Float16)d.x, (_Float16)d.y};
        }
    }
    const float br_ = bhh[j], bz_ = bhh[j + HH], bn_ = bhh[j + 2 * HH];

    float hreg = 0.f;
    if (tid < HH) hb[0][tid] = (_Float16)0.f;
    const float* gb = gi + (size_t)b * SEQ * NG;

    // depth-4 prefetch registers (static names; reloads target t+4)
    float gAr=0, gAz=0, gAn=0, gBr=0, gBz=0, gBn=0;
    float gCr=0, gCz=0, gCn=0, gDr=0, gDz=0, gDn=0;
    if (half == 0) {
        const float* g0 = gb;               gAr = g0[j]; gAz = g0[j+HH]; gAn = g0[j+2*HH];
        const float* g1 = gb + NG;          gBr = g1[j]; gBz = g1[j+HH]; gBn = g1[j+2*HH];
        const float* g2 = gb + 2 * NG;      gCr = g2[j]; gCz = g2[j+HH]; gCn = g2[j+2*HH];
        const float* g3 = gb + 3 * NG;      gDr = g3[j]; gDz = g3[j+HH]; gDn = g3[j+2*HH];
    }
    BAR_LDS();

    // NOTE: prefetch for t+4 at the last iteration reads up to gi row SEQ+3,
    // which lands in the s/hf/hb scratch regions (allocated) - never consumed.
#define GRU_BODY(P, GR, GZ, GN, TOFF)                                          \
    {                                                                          \
        float ar = 0.f, az = 0.f, an = 0.f;                                    \
        const uint4* hp = (const uint4*)&hb[P][half * 64];                     \
        _Pragma("unroll")                                                      \
        for (int i = 0; i < 8; ++i) {                                          \
            union { uint4 u; f16x2 h2[4]; } U;                                 \
            U.u = hp[i];                                                       \
            _Pragma("unroll")                                                  \
            for (int k = 0; k < 4; ++k) {                                      \
                ar = __builtin_amdgcn_fdot2(wr_[i*4+k], U.h2[k], ar, false);   \
                az = __builtin_amdgcn_fdot2(wz_[i*4+k], U.h2[k], az, false);   \
                an = __builtin_amdgcn_fdot2(wn_[i*4+k], U.h2[k], an, false);   \
            }                                                                  \
        }                                                                      \
        if (half) { ps_r[j] = ar; ps_z[j] = az; ps_n[j] = an; }                \
        BAR_LDS();                                                             \
        if (!half) {                                                           \
            const float Ar = ar + ps_r[j];                                     \
            const float Az = az + ps_z[j];                                     \
            const float An = an + ps_n[j];                                     \
            const float r = fsig(GR + Ar + br_);                               \
            const float z = fsig(GZ + Az + bz_);                               \
            const float n = ftanh(GN + r * (An + bn_));                        \
            hreg = (1.f - z) * n + z * hreg;                                   \
            hb[P ^ 1][j] = (_Float16)hreg;                                     \
            const float* gnext = gb + (size_t)(t + (TOFF) + 4) * NG;           \
            GR = gnext[j]; GZ = gnext[j + HH]; GN = gnext[j + 2 * HH];         \
        }                                                                      \
        BAR_LDS();                                                             \
    }

    for (int t = 0; t < SEQ; t += 4) {
        GRU_BODY(0, gAr, gAz, gAn, 0)
        GRU_BODY(1, gBr, gBz, gBn, 1)
        GRU_BODY(0, gCr, gCz, gCn, 2)
        GRU_BODY(1, gDr, gDz, gDn, 3)
    }
#undef GRU_BODY
    if (!half) hout[b * HH + j] = hreg;
}

// ---------------------------------------------------------------------------
__global__ __launch_bounds__(384) void gru_bwd(const float* __restrict__ X,
                                               const float* __restrict__ mask,
                                               const float* __restrict__ Wih,
                                               const float* __restrict__ bih,
                                               const float* __restrict__ bhh,
                                               float* __restrict__ hout) {
    const int b = blockIdx.x, j = threadIdx.x;
    __shared__ float gib[NG];
    const float* xr = X + ((size_t)b * SEQ + (SEQ - 1)) * EMB;
    const float  mv = mask[(size_t)b * SEQ + SEQ - 1];
    const float* wr_ = Wih + (size_t)j * EMB;
    float acc = 0.f;
    for (int e = 0; e < EMB; ++e) acc += xr[e] * wr_[e];
    gib[j] = acc * mv + bih[j];
    __syncthreads();
    if (j < HH) {
        const float r = fsig(gib[j] + bhh[j]);
        const float z = fsig(gib[j + HH] + bhh[j + HH]);
        const float n = ftanh(gib[j + 2 * HH] + r * bhh[j + 2 * HH]);
        hout[b * HH + j] = (1.f - z) * n;
    }
}

// ---------------------------------------------------------------------------
__global__ __launch_bounds__(128) void mlp(const float* __restrict__ hf,
                                           const float* __restrict__ hb,
                                           const float* __restrict__ s,
                                           const float* __restrict__ W1, const float* __restrict__ b1,
                                           const float* __restrict__ W2, const float* __restrict__ b2,
                                           const float* __restrict__ W3, const float* __restrict__ b3,
                                           float* __restrict__ out) {
    const int b = blockIdx.x, j = threadIdx.x;
    __shared__ float zin[2 * HH + EMB];   // 556
    __shared__ float l1[128];
    __shared__ float l2[64];
    zin[j]      = hf[b * HH + j];
    zin[HH + j] = hb[b * HH + j];
    for (int e = j; e < EMB; e += 128) {
        float v = s[b * EMB + e];
        zin[2 * HH + e] = v * v;
    }
    __syncthreads();
    {
        float a = b1[j];
        const float* w = W1 + (size_t)j * (2 * HH + EMB);
        for (int i = 0; i < 2 * HH + EMB; ++i) a += zin[i] * w[i];
        l1[j] = fmaxf(a, 0.f);
    }
    __syncthreads();
    if (j < 64) {
        float a = b2[j];
        const float* w = W2 + (size_t)j * 128;
        for (int i = 0; i < 128; ++i) a += l1[i] * w[i];
        l2[j] = fmaxf(a, 0.f);
    }
    __syncthreads();
    if (j < 23) {
        float a = b3[j];
        const float* w = W3 + (size_t)j * 64;
        for (int i = 0; i < 64; ++i) a += l2[i] * w[i];
        out[b * 23 + j] = a;
    }
}

// ---------------------------------------------------------------------------
extern "C" void kernel_launch(void* const* d_in, const int* in_sizes, int n_in,
                              void* d_out, int out_size, void* d_ws, size_t ws_size,
                              hipStream_t stream) {
    const float* x     = (const float*)d_in[0];
    const float* mask  = (const float*)d_in[2];
    const float* Wih_f = (const float*)d_in[3];
    const float* Whh_f = (const float*)d_in[4];
    const float* bih_f = (const float*)d_in[5];
    const float* bhh_f = (const float*)d_in[6];
    const float* Wih_b = (const float*)d_in[7];
    const float* bih_b = (const float*)d_in[9];
    const float* bhh_b = (const float*)d_in[10];
    const float* W1 = (const float*)d_in[11];
    const float* b1 = (const float*)d_in[12];
    const float* W2 = (const float*)d_in[13];
    const float* b2 = (const float*)d_in[14];
    const float* W3 = (const float*)d_in[15];
    const float* b3 = (const float*)d_in[16];
    float* out = (float*)d_out;

    float* gi = (float*)d_ws;                       // 65536*384 f32 = 96 MB
    float* s  = gi + (size_t)BS * SEQ * NG;         // 64*300
    float* hf = s  + BS * EMB;                      // 64*128
    float* hb = hf + BS * HH;                       // 64*128

    gi_gemm<<<dim3(512, 3), dim3(256), 0, stream>>>(x, mask, Wih_f, bih_f, gi);
    col_sum<<<dim3(BS, 2), dim3(256), 0, stream>>>(x, mask, s);
    gru_scan<<<dim3(BS), dim3(256), 0, stream>>>(gi, Whh_f, bhh_f, hf);
    gru_bwd<<<dim3(BS), dim3(384), 0, stream>>>(x, mask, Wih_b, bih_b, bhh_b, hb);
    mlp<<<dim3(BS), dim3(128), 0, stream>>>(hf, hb, s, W1, b1, W2, b2, W3, b3, out);
}

// Round 5
// 584.977 us; speedup vs baseline: 1.1496x; 1.1496x over previous
//
#include <hip/hip_runtime.h>
#include <hip/hip_bf16.h>

#define HH   128
#define EMB  300
#define SEQ  1024
#define BS   64
#define NG   384   // 3*H
#define NCHUNK 8   // col_sum t-chunks

typedef __attribute__((ext_vector_type(8))) short  bf16x8;
typedef __attribute__((ext_vector_type(4))) float  f32x4;
typedef _Float16 f16x2 __attribute__((ext_vector_type(2)));

__device__ __forceinline__ unsigned short f2bf(float f) {
    unsigned int u = __float_as_uint(f);
    unsigned int r = (u + 0x7fffu + ((u >> 16) & 1u)) >> 16;   // RNE
    return (unsigned short)r;
}
__device__ __forceinline__ float fexp(float x) { return __builtin_amdgcn_exp2f(x * 1.44269504088896f); }
__device__ __forceinline__ float fsig(float x) { return __builtin_amdgcn_rcpf(1.f + fexp(-x)); }
__device__ __forceinline__ float ftanh(float x){ return __builtin_amdgcn_rcpf(1.f + fexp(-2.f*x)) * 2.f - 1.f; }

// LDS-only barrier: drains LDS ops but leaves global loads in flight.
#define BAR_LDS() asm volatile("s_waitcnt lgkmcnt(0)\n\ts_barrier" ::: "memory")

// ---------------------------------------------------------------------------
// gi[r, j] = (sum_e X[r,e]*mask[r]*W[j,e]) + bias[j]
// ---------------------------------------------------------------------------
__global__ __launch_bounds__(256) void gi_gemm(const float* __restrict__ X,
                                               const float* __restrict__ mask,
                                               const float* __restrict__ W,
                                               const float* __restrict__ bias,
                                               float* __restrict__ out) {
    __shared__ __align__(16) unsigned short As[128 * 32];
    __shared__ __align__(16) unsigned short Bs[128 * 32];
    const int m0   = blockIdx.x * 128;
    const int n0   = blockIdx.y * 128;
    const int tid  = threadIdx.x;
    const int row  = tid >> 1;            // 0..127
    const int seg  = tid & 1;             // 16-col half
    const int wave = tid >> 6;
    const int lane = tid & 63;
    const int wr   = wave >> 1, wc = wave & 1;
    const int r16  = lane & 15, kg = lane >> 4;

    f32x4 acc[4][4];
    #pragma unroll
    for (int m = 0; m < 4; ++m)
        #pragma unroll
        for (int n = 0; n < 4; ++n) acc[m][n] = (f32x4){0.f,0.f,0.f,0.f};

    const float mrow = mask[m0 + row];

    for (int k0 = 0; k0 < 320; k0 += 32) {
        // ---- stage A (x * mask -> bf16) ----
        {
            const float* src = X + (size_t)(m0 + row) * EMB + k0 + seg * 16;
            unsigned short tmp[16];
            if (k0 + seg * 16 + 15 < EMB) {
                #pragma unroll
                for (int i = 0; i < 4; ++i) {
                    float4 v = ((const float4*)src)[i];
                    tmp[i*4+0] = f2bf(v.x * mrow);
                    tmp[i*4+1] = f2bf(v.y * mrow);
                    tmp[i*4+2] = f2bf(v.z * mrow);
                    tmp[i*4+3] = f2bf(v.w * mrow);
                }
            } else {
                #pragma unroll
                for (int i = 0; i < 16; ++i) {
                    int c = k0 + seg * 16 + i;
                    float v = (c < EMB) ? src[i] : 0.f;
                    tmp[i] = f2bf(v * mrow);
                }
            }
            uint4* dst = (uint4*)&As[row * 32 + seg * 16];
            dst[0] = ((const uint4*)tmp)[0];
            dst[1] = ((const uint4*)tmp)[1];
        }
        // ---- stage B (W -> bf16) ----
        {
            const float* src = W + (size_t)(n0 + row) * EMB + k0 + seg * 16;
            unsigned short tmp[16];
            if (k0 + seg * 16 + 15 < EMB) {
                #pragma unroll
                for (int i = 0; i < 4; ++i) {
                    float4 v = ((const float4*)src)[i];
                    tmp[i*4+0] = f2bf(v.x);
                    tmp[i*4+1] = f2bf(v.y);
                    tmp[i*4+2] = f2bf(v.z);
                    tmp[i*4+3] = f2bf(v.w);
                }
            } else {
                #pragma unroll
                for (int i = 0; i < 16; ++i) {
                    int c = k0 + seg * 16 + i;
                    float v = (c < EMB) ? src[i] : 0.f;
                    tmp[i] = f2bf(v);
                }
            }
            uint4* dst = (uint4*)&Bs[row * 32 + seg * 16];
            dst[0] = ((const uint4*)tmp)[0];
            dst[1] = ((const uint4*)tmp)[1];
        }
        __syncthreads();

        bf16x8 a[4], bfr[4];
        #pragma unroll
        for (int m = 0; m < 4; ++m)
            a[m] = *(const bf16x8*)&As[(wr * 64 + m * 16 + r16) * 32 + kg * 8];
        #pragma unroll
        for (int n = 0; n < 4; ++n)
            bfr[n] = *(const bf16x8*)&Bs[(wc * 64 + n * 16 + r16) * 32 + kg * 8];
        #pragma unroll
        for (int m = 0; m < 4; ++m)
            #pragma unroll
            for (int n = 0; n < 4; ++n)
                acc[m][n] = __builtin_amdgcn_mfma_f32_16x16x32_bf16(a[m], bfr[n], acc[m][n], 0, 0, 0);
        __syncthreads();
    }

    // ---- epilogue ----
    #pragma unroll
    for (int m = 0; m < 4; ++m) {
        const int rowb = m0 + wr * 64 + m * 16 + (lane >> 4) * 4;
        #pragma unroll
        for (int n = 0; n < 4; ++n) {
            const int col = n0 + wc * 64 + n * 16 + r16;
            const float bj = bias[col];
            #pragma unroll
            for (int q = 0; q < 4; ++q)
                out[(size_t)(rowb + q) * NG + col] = acc[m][n][q] + bj;
        }
    }
}

// ---------------------------------------------------------------------------
// partial column sums: spart[(b*NCHUNK + c)][e] = sum over 128 t's
// ---------------------------------------------------------------------------
__global__ __launch_bounds__(320) void col_sum(const float* __restrict__ X,
                                               const float* __restrict__ mask,
                                               float* __restrict__ spart) {
    const int b = blockIdx.x, c = blockIdx.y;
    const int e = threadIdx.x;
    if (e >= EMB) return;
    const int tchunk = SEQ / NCHUNK;   // 128
    float acc = 0.f;
    const float* xb = X + ((size_t)b * SEQ + (size_t)c * tchunk) * EMB;
    const float* mb = mask + (size_t)b * SEQ + (size_t)c * tchunk;
    for (int t = 0; t < tchunk; ++t)
        acc += xb[(size_t)t * EMB + e] * mb[t];
    spart[((size_t)b * NCHUNK + c) * EMB + e] = acc;
}

// ---------------------------------------------------------------------------
// forward GRU scan, 256 threads. Output j = tid>>1, k-half = tid&1: the two
// half-dots of each output live in ADJACENT LANES of one wave; combine is a
// DPP shfl_xor (no LDS, no extra barrier). Both lanes compute gates
// redundantly. One barrier per step (double-buffered h). gi prefetched 4
// steps ahead in static register sets; BAR_LDS keeps them in flight.
// ---------------------------------------------------------------------------
__global__ __launch_bounds__(256, 1) void gru_scan(const float* __restrict__ gi,
                                                   const float* __restrict__ Whh,
                                                   const float* __restrict__ bhh,
                                                   float* __restrict__ hout) {
    const int b    = blockIdx.x;
    const int tid  = threadIdx.x;
    const int j    = tid >> 1;           // 0..127 output index
    const int half = tid & 1;            // k-half (adjacent lanes)
    __shared__ __align__(16) _Float16 hb[2][HH];

    // ---- weights: rows j, j+HH, j+2HH, cols [half*64, half*64+64) ----
    f16x2 wr_[32], wz_[32], wn_[32];
    {
        const float2* r0 = (const float2*)(Whh + (size_t)j * HH            + half * 64);
        const float2* r1 = (const float2*)(Whh + (size_t)(j + HH) * HH     + half * 64);
        const float2* r2 = (const float2*)(Whh + (size_t)(j + 2 * HH) * HH + half * 64);
        #pragma unroll
        for (int i = 0; i < 32; ++i) {
            float2 a = r0[i], c = r1[i], d = r2[i];
            wr_[i] = (f16x2){(_Float16)a.x, (_Float16)a.y};
            wz_[i] = (f16x2){(_Float16)c.x, (_Float16)c.y};
            wn_[i] = (f16x2){(_Float16)d.x, (_Float16)d.y};
        }
    }
    const float br_ = bhh[j], bz_ = bhh[j + HH], bn_ = bhh[j + 2 * HH];

    float hreg = 0.f;
    if (tid < HH) hb[0][tid] = (_Float16)0.f;
    const float* gb = gi + (size_t)b * SEQ * NG;

    // depth-4 prefetch registers (static names; reloads target t+4)
    float gAr, gAz, gAn, gBr, gBz, gBn, gCr, gCz, gCn, gDr, gDz, gDn;
    {
        const float* g0 = gb;               gAr = g0[j]; gAz = g0[j+HH]; gAn = g0[j+2*HH];
        const float* g1 = gb + NG;          gBr = g1[j]; gBz = g1[j+HH]; gBn = g1[j+2*HH];
        const float* g2 = gb + 2 * NG;      gCr = g2[j]; gCz = g2[j+HH]; gCn = g2[j+2*HH];
        const float* g3 = gb + 3 * NG;      gDr = g3[j]; gDz = g3[j+HH]; gDn = g3[j+2*HH];
    }
    BAR_LDS();

    // NOTE: prefetch for t+4 in the final iterations reads past gi's end into
    // the spart/hf/hb scratch regions (allocated) — loaded but never consumed.
#define GRU_BODY(P, GR, GZ, GN, TOFF)                                          \
    {                                                                          \
        float ar = 0.f, az = 0.f, an = 0.f;                                    \
        const uint4* hp = (const uint4*)&hb[P][half * 64];                     \
        _Pragma("unroll")                                                      \
        for (int i = 0; i < 8; ++i) {                                          \
            union { uint4 u; f16x2 h2[4]; } U;                                 \
            U.u = hp[i];                                                       \
            _Pragma("unroll")                                                  \
            for (int k = 0; k < 4; ++k) {                                      \
                ar = __builtin_amdgcn_fdot2(wr_[i*4+k], U.h2[k], ar, false);   \
                az = __builtin_amdgcn_fdot2(wz_[i*4+k], U.h2[k], az, false);   \
                an = __builtin_amdgcn_fdot2(wn_[i*4+k], U.h2[k], an, false);   \
            }                                                                  \
        }                                                                      \
        ar += __shfl_xor(ar, 1);                                               \
        az += __shfl_xor(az, 1);                                               \
        an += __shfl_xor(an, 1);                                               \
        const float r = fsig(GR + ar + br_);                                   \
        const float z = fsig(GZ + az + bz_);                                   \
        const float n = ftanh(GN + r * (an + bn_));                            \
        hreg = (1.f - z) * n + z * hreg;                                       \
        hb[P ^ 1][j] = (_Float16)hreg;                                         \
        const float* gnext = gb + (size_t)(t + (TOFF) + 4) * NG;               \
        GR = gnext[j]; GZ = gnext[j + HH]; GN = gnext[j + 2 * HH];              \
        BAR_LDS();                                                             \
    }

    for (int t = 0; t < SEQ; t += 4) {
        GRU_BODY(0, gAr, gAz, gAn, 0)
        GRU_BODY(1, gBr, gBz, gBn, 1)
        GRU_BODY(0, gCr, gCz, gCn, 2)
        GRU_BODY(1, gDr, gDz, gDn, 3)
    }
#undef GRU_BODY
    if (!half) hout[b * HH + j] = hreg;
}

// ---------------------------------------------------------------------------
__global__ __launch_bounds__(384) void gru_bwd(const float* __restrict__ X,
                                               const float* __restrict__ mask,
                                               const float* __restrict__ Wih,
                                               const float* __restrict__ bih,
                                               const float* __restrict__ bhh,
                                               float* __restrict__ hout) {
    const int b = blockIdx.x, j = threadIdx.x;
    __shared__ float gib[NG];
    const float* xr = X + ((size_t)b * SEQ + (SEQ - 1)) * EMB;
    const float  mv = mask[(size_t)b * SEQ + SEQ - 1];
    const float* wr_ = Wih + (size_t)j * EMB;
    float acc = 0.f;
    for (int e = 0; e < EMB; ++e) acc += xr[e] * wr_[e];
    gib[j] = acc * mv + bih[j];
    __syncthreads();
    if (j < HH) {
        const float r = fsig(gib[j] + bhh[j]);
        const float z = fsig(gib[j + HH] + bhh[j + HH]);
        const float n = ftanh(gib[j + 2 * HH] + r * bhh[j + 2 * HH]);
        hout[b * HH + j] = (1.f - z) * n;
    }
}

// ---------------------------------------------------------------------------
__global__ __launch_bounds__(128) void mlp(const float* __restrict__ hf,
                                           const float* __restrict__ hb,
                                           const float* __restrict__ spart,
                                           const float* __restrict__ W1, const float* __restrict__ b1,
                                           const float* __restrict__ W2, const float* __restrict__ b2,
                                           const float* __restrict__ W3, const float* __restrict__ b3,
                                           float* __restrict__ out) {
    const int b = blockIdx.x, j = threadIdx.x;
    __shared__ float zin[2 * HH + EMB];   // 556
    __shared__ float l1[128];
    __shared__ float l2[64];
    zin[j]      = hf[b * HH + j];
    zin[HH + j] = hb[b * HH + j];
    for (int e = j; e < EMB; e += 128) {
        float v = 0.f;
        #pragma unroll
        for (int c = 0; c < NCHUNK; ++c)
            v += spart[((size_t)b * NCHUNK + c) * EMB + e];
        zin[2 * HH + e] = v * v;
    }
    __syncthreads();
    {
        float a = b1[j];
        const float* w = W1 + (size_t)j * (2 * HH + EMB);
        for (int i = 0; i < 2 * HH + EMB; ++i) a += zin[i] * w[i];
        l1[j] = fmaxf(a, 0.f);
    }
    __syncthreads();
    if (j < 64) {
        float a = b2[j];
        const float* w = W2 + (size_t)j * 128;
        for (int i = 0; i < 128; ++i) a += l1[i] * w[i];
        l2[j] = fmaxf(a, 0.f);
    }
    __syncthreads();
    if (j < 23) {
        float a = b3[j];
        const float* w = W3 + (size_t)j * 64;
        for (int i = 0; i < 64; ++i) a += l2[i] * w[i];
        out[b * 23 + j] = a;
    }
}

// ---------------------------------------------------------------------------
extern "C" void kernel_launch(void* const* d_in, const int* in_sizes, int n_in,
                              void* d_out, int out_size, void* d_ws, size_t ws_size,
                              hipStream_t stream) {
    const float* x     = (const float*)d_in[0];
    const float* mask  = (const float*)d_in[2];
    const float* Wih_f = (const float*)d_in[3];
    const float* Whh_f = (const float*)d_in[4];
    const float* bih_f = (const float*)d_in[5];
    const float* bhh_f = (const float*)d_in[6];
    const float* Wih_b = (const float*)d_in[7];
    const float* bih_b = (const float*)d_in[9];
    const float* bhh_b = (const float*)d_in[10];
    const float* W1 = (const float*)d_in[11];
    const float* b1 = (const float*)d_in[12];
    const float* W2 = (const float*)d_in[13];
    const float* b2 = (const float*)d_in[14];
    const float* W3 = (const float*)d_in[15];
    const float* b3 = (const float*)d_in[16];
    float* out = (float*)d_out;

    float* gi    = (float*)d_ws;                          // 64*1024*384 f32
    float* spart = gi + (size_t)BS * SEQ * NG;            // 64*8*300
    float* hf    = spart + (size_t)BS * NCHUNK * EMB;     // 64*128
    float* hb    = hf + BS * HH;                          // 64*128

    gi_gemm<<<dim3(512, 3), dim3(256), 0, stream>>>(x, mask, Wih_f, bih_f, gi);
    col_sum<<<dim3(BS, NCHUNK), dim3(320), 0, stream>>>(x, mask, spart);
    gru_scan<<<dim3(BS), dim3(256), 0, stream>>>(gi, Whh_f, bhh_f, hf);
    gru_bwd<<<dim3(BS), dim3(384), 0, stream>>>(x, mask, Wih_b, bih_b, bhh_b, hb);
    mlp<<<dim3(BS), dim3(128), 0, stream>>>(hf, hb, spart, W1, b1, W2, b2, W3, b3, out);
}

// Round 6
// 527.116 us; speedup vs baseline: 1.2758x; 1.1098x over previous
//
#include <hip/hip_runtime.h>
#include <hip/hip_bf16.h>

#define HH   128
#define EMB  300
#define SEQ  1024
#define BS   64
#define NG   384   // 3*H
#define NCHUNK 8   // col_sum t-chunks

typedef __attribute__((ext_vector_type(8))) short  bf16x8;
typedef __attribute__((ext_vector_type(4))) float  f32x4;
typedef _Float16 f16x2 __attribute__((ext_vector_type(2)));

__device__ __forceinline__ unsigned short f2bf(float f) {
    unsigned int u = __float_as_uint(f);
    unsigned int r = (u + 0x7fffu + ((u >> 16) & 1u)) >> 16;   // RNE
    return (unsigned short)r;
}
__device__ __forceinline__ float fexp(float x) { return __builtin_amdgcn_exp2f(x * 1.44269504088896f); }
__device__ __forceinline__ float fsig(float x) { return __builtin_amdgcn_rcpf(1.f + fexp(-x)); }
__device__ __forceinline__ float ftanh(float x){ return __builtin_amdgcn_rcpf(1.f + fexp(-2.f*x)) * 2.f - 1.f; }

// add the value from the adjacent lane (lane^1) via DPP quad_perm(1,0,3,2)
// — pure VALU, unlike __shfl_xor which lowers to ds_bpermute (LDS pipe).
__device__ __forceinline__ float dpp_pair_add(float x) {
    int y = __builtin_amdgcn_mov_dpp(__float_as_int(x), 0xB1, 0xF, 0xF, true);
    return x + __int_as_float(y);
}

// LDS-only barrier: drains LDS ops but leaves global loads in flight.
#define BAR_LDS() asm volatile("s_waitcnt lgkmcnt(0)\n\ts_barrier" ::: "memory")

// ---------------------------------------------------------------------------
// gi[r, j] = (sum_e X[r,e]*mask[r]*W[j,e]) + bias[j]
// ---------------------------------------------------------------------------
__global__ __launch_bounds__(256) void gi_gemm(const float* __restrict__ X,
                                               const float* __restrict__ mask,
                                               const float* __restrict__ W,
                                               const float* __restrict__ bias,
                                               float* __restrict__ out) {
    __shared__ __align__(16) unsigned short As[128 * 32];
    __shared__ __align__(16) unsigned short Bs[128 * 32];
    const int m0   = blockIdx.x * 128;
    const int n0   = blockIdx.y * 128;
    const int tid  = threadIdx.x;
    const int row  = tid >> 1;            // 0..127
    const int seg  = tid & 1;             // 16-col half
    const int wave = tid >> 6;
    const int lane = tid & 63;
    const int wr   = wave >> 1, wc = wave & 1;
    const int r16  = lane & 15, kg = lane >> 4;

    f32x4 acc[4][4];
    #pragma unroll
    for (int m = 0; m < 4; ++m)
        #pragma unroll
        for (int n = 0; n < 4; ++n) acc[m][n] = (f32x4){0.f,0.f,0.f,0.f};

    const float mrow = mask[m0 + row];

    for (int k0 = 0; k0 < 320; k0 += 32) {
        // ---- stage A (x * mask -> bf16) ----
        {
            const float* src = X + (size_t)(m0 + row) * EMB + k0 + seg * 16;
            unsigned short tmp[16];
            if (k0 + seg * 16 + 15 < EMB) {
                #pragma unroll
                for (int i = 0; i < 4; ++i) {
                    float4 v = ((const float4*)src)[i];
                    tmp[i*4+0] = f2bf(v.x * mrow);
                    tmp[i*4+1] = f2bf(v.y * mrow);
                    tmp[i*4+2] = f2bf(v.z * mrow);
                    tmp[i*4+3] = f2bf(v.w * mrow);
                }
            } else {
                #pragma unroll
                for (int i = 0; i < 16; ++i) {
                    int c = k0 + seg * 16 + i;
                    float v = (c < EMB) ? src[i] : 0.f;
                    tmp[i] = f2bf(v * mrow);
                }
            }
            uint4* dst = (uint4*)&As[row * 32 + seg * 16];
            dst[0] = ((const uint4*)tmp)[0];
            dst[1] = ((const uint4*)tmp)[1];
        }
        // ---- stage B (W -> bf16) ----
        {
            const float* src = W + (size_t)(n0 + row) * EMB + k0 + seg * 16;
            unsigned short tmp[16];
            if (k0 + seg * 16 + 15 < EMB) {
                #pragma unroll
                for (int i = 0; i < 4; ++i) {
                    float4 v = ((const float4*)src)[i];
                    tmp[i*4+0] = f2bf(v.x);
                    tmp[i*4+1] = f2bf(v.y);
                    tmp[i*4+2] = f2bf(v.z);
                    tmp[i*4+3] = f2bf(v.w);
                }
            } else {
                #pragma unroll
                for (int i = 0; i < 16; ++i) {
                    int c = k0 + seg * 16 + i;
                    float v = (c < EMB) ? src[i] : 0.f;
                    tmp[i] = f2bf(v);
                }
            }
            uint4* dst = (uint4*)&Bs[row * 32 + seg * 16];
            dst[0] = ((const uint4*)tmp)[0];
            dst[1] = ((const uint4*)tmp)[1];
        }
        __syncthreads();

        bf16x8 a[4], bfr[4];
        #pragma unroll
        for (int m = 0; m < 4; ++m)
            a[m] = *(const bf16x8*)&As[(wr * 64 + m * 16 + r16) * 32 + kg * 8];
        #pragma unroll
        for (int n = 0; n < 4; ++n)
            bfr[n] = *(const bf16x8*)&Bs[(wc * 64 + n * 16 + r16) * 32 + kg * 8];
        #pragma unroll
        for (int m = 0; m < 4; ++m)
            #pragma unroll
            for (int n = 0; n < 4; ++n)
                acc[m][n] = __builtin_amdgcn_mfma_f32_16x16x32_bf16(a[m], bfr[n], acc[m][n], 0, 0, 0);
        __syncthreads();
    }

    // ---- epilogue ----
    #pragma unroll
    for (int m = 0; m < 4; ++m) {
        const int rowb = m0 + wr * 64 + m * 16 + (lane >> 4) * 4;
        #pragma unroll
        for (int n = 0; n < 4; ++n) {
            const int col = n0 + wc * 64 + n * 16 + r16;
            const float bj = bias[col];
            #pragma unroll
            for (int q = 0; q < 4; ++q)
                out[(size_t)(rowb + q) * NG + col] = acc[m][n][q] + bj;
        }
    }
}

// ---------------------------------------------------------------------------
// partial column sums: spart[(b*NCHUNK + c)][e] = sum over 128 t's
// ---------------------------------------------------------------------------
__global__ __launch_bounds__(320) void col_sum(const float* __restrict__ X,
                                               const float* __restrict__ mask,
                                               float* __restrict__ spart) {
    const int b = blockIdx.x, c = blockIdx.y;
    const int e = threadIdx.x;
    if (e >= EMB) return;
    const int tchunk = SEQ / NCHUNK;   // 128
    float acc = 0.f;
    const float* xb = X + ((size_t)b * SEQ + (size_t)c * tchunk) * EMB;
    const float* mb = mask + (size_t)b * SEQ + (size_t)c * tchunk;
    for (int t = 0; t < tchunk; ++t)
        acc += xb[(size_t)t * EMB + e] * mb[t];
    spart[((size_t)b * NCHUNK + c) * EMB + e] = acc;
}

// ---------------------------------------------------------------------------
// forward GRU scan, 256 threads. Output j = tid>>1, k-half = tid&1: the two
// half-dots of each output live in ADJACENT LANES of one wave; combine is a
// DPP quad-perm add (pure VALU). One barrier per step (double-buffered h).
// gi prefetched 4 steps ahead via incremental pointers pA..pD.
// ---------------------------------------------------------------------------
__global__ __launch_bounds__(256, 1) void gru_scan(const float* __restrict__ gi,
                                                   const float* __restrict__ Whh,
                                                   const float* __restrict__ bhh,
                                                   float* __restrict__ hout) {
    const int b    = blockIdx.x;
    const int tid  = threadIdx.x;
    const int j    = tid >> 1;           // 0..127 output index
    const int half = tid & 1;            // k-half (adjacent lanes)
    __shared__ __align__(16) _Float16 hb[2][HH];

    // ---- weights: rows j, j+HH, j+2HH, cols [half*64, half*64+64) ----
    f16x2 wr_[32], wz_[32], wn_[32];
    {
        const float2* r0 = (const float2*)(Whh + (size_t)j * HH            + half * 64);
        const float2* r1 = (const float2*)(Whh + (size_t)(j + HH) * HH     + half * 64);
        const float2* r2 = (const float2*)(Whh + (size_t)(j + 2 * HH) * HH + half * 64);
        #pragma unroll
        for (int i = 0; i < 32; ++i) {
            float2 a = r0[i], c = r1[i], d = r2[i];
            wr_[i] = (f16x2){(_Float16)a.x, (_Float16)a.y};
            wz_[i] = (f16x2){(_Float16)c.x, (_Float16)c.y};
            wn_[i] = (f16x2){(_Float16)d.x, (_Float16)d.y};
        }
    }
    const float br_ = bhh[j], bz_ = bhh[j + HH], bn_ = bhh[j + 2 * HH];

    float hreg = 0.f;
    if (tid < HH) hb[0][tid] = (_Float16)0.f;
    const float* gb = gi + (size_t)b * SEQ * NG;

    // depth-4 prefetch registers + incremental source pointers
    float gAr, gAz, gAn, gBr, gBz, gBn, gCr, gCz, gCn, gDr, gDz, gDn;
    {
        const float* g0 = gb;               gAr = g0[j]; gAz = g0[j+HH]; gAn = g0[j+2*HH];
        const float* g1 = gb + NG;          gBr = g1[j]; gBz = g1[j+HH]; gBn = g1[j+2*HH];
        const float* g2 = gb + 2 * NG;      gCr = g2[j]; gCz = g2[j+HH]; gCn = g2[j+2*HH];
        const float* g3 = gb + 3 * NG;      gDr = g3[j]; gDz = g3[j+HH]; gDn = g3[j+2*HH];
    }
    const float* pA = gb + 4 * NG;
    const float* pB = gb + 5 * NG;
    const float* pC = gb + 6 * NG;
    const float* pD = gb + 7 * NG;
    BAR_LDS();

    // NOTE: prefetch in the final iterations reads past gi's end into the
    // spart/hf/hb scratch regions (allocated) — loaded but never consumed.
#define GRU_BODY(P, GR, GZ, GN, PP)                                            \
    {                                                                          \
        float ar[2] = {0.f, 0.f}, az[2] = {0.f, 0.f}, an[2] = {0.f, 0.f};      \
        const uint4* hp = (const uint4*)&hb[P][half * 64];                     \
        _Pragma("unroll")                                                      \
        for (int i = 0; i < 8; ++i) {                                          \
            union { uint4 u; f16x2 h2[4]; } U;                                 \
            U.u = hp[i];                                                       \
            _Pragma("unroll")                                                  \
            for (int k = 0; k < 4; ++k) {                                      \
                ar[k&1] = __builtin_amdgcn_fdot2(wr_[i*4+k], U.h2[k], ar[k&1], false); \
                az[k&1] = __builtin_amdgcn_fdot2(wz_[i*4+k], U.h2[k], az[k&1], false); \
                an[k&1] = __builtin_amdgcn_fdot2(wn_[i*4+k], U.h2[k], an[k&1], false); \
            }                                                                  \
        }                                                                      \
        const float arf = dpp_pair_add(ar[0] + ar[1]);                         \
        const float azf = dpp_pair_add(az[0] + az[1]);                         \
        const float anf = dpp_pair_add(an[0] + an[1]);                         \
        const float r = fsig(GR + arf + br_);                                  \
        const float z = fsig(GZ + azf + bz_);                                  \
        const float n = ftanh(GN + r * (anf + bn_));                           \
        hreg = n + z * (hreg - n);                                             \
        hb[P ^ 1][j] = (_Float16)hreg;                                         \
        GR = PP[j]; GZ = PP[j + HH]; GN = PP[j + 2 * HH];                      \
        PP += 4 * NG;                                                          \
        BAR_LDS();                                                             \
    }

    for (int it = 0; it < SEQ / 4; ++it) {
        GRU_BODY(0, gAr, gAz, gAn, pA)
        GRU_BODY(1, gBr, gBz, gBn, pB)
        GRU_BODY(0, gCr, gCz, gCn, pC)
        GRU_BODY(1, gDr, gDz, gDn, pD)
    }
#undef GRU_BODY
    if (!half) hout[b * HH + j] = hreg;
}

// ---------------------------------------------------------------------------
__global__ __launch_bounds__(384) void gru_bwd(const float* __restrict__ X,
                                               const float* __restrict__ mask,
                                               const float* __restrict__ Wih,
                                               const float* __restrict__ bih,
                                               const float* __restrict__ bhh,
                                               float* __restrict__ hout) {
    const int b = blockIdx.x, j = threadIdx.x;
    __shared__ float gib[NG];
    const float* xr = X + ((size_t)b * SEQ + (SEQ - 1)) * EMB;
    const float  mv = mask[(size_t)b * SEQ + SEQ - 1];
    const float* wr_ = Wih + (size_t)j * EMB;
    float acc = 0.f;
    for (int e = 0; e < EMB; ++e) acc += xr[e] * wr_[e];
    gib[j] = acc * mv + bih[j];
    __syncthreads();
    if (j < HH) {
        const float r = fsig(gib[j] + bhh[j]);
        const float z = fsig(gib[j + HH] + bhh[j + HH]);
        const float n = ftanh(gib[j + 2 * HH] + r * bhh[j + 2 * HH]);
        hout[b * HH + j] = (1.f - z) * n;
    }
}

// ---------------------------------------------------------------------------
__global__ __launch_bounds__(128) void mlp(const float* __restrict__ hf,
                                           const float* __restrict__ hb,
                                           const float* __restrict__ spart,
                                           const float* __restrict__ W1, const float* __restrict__ b1,
                                           const float* __restrict__ W2, const float* __restrict__ b2,
                                           const float* __restrict__ W3, const float* __restrict__ b3,
                                           float* __restrict__ out) {
    const int b = blockIdx.x, j = threadIdx.x;
    __shared__ float zin[2 * HH + EMB];   // 556
    __shared__ float l1[128];
    __shared__ float l2[64];
    zin[j]      = hf[b * HH + j];
    zin[HH + j] = hb[b * HH + j];
    for (int e = j; e < EMB; e += 128) {
        float v = 0.f;
        #pragma unroll
        for (int c = 0; c < NCHUNK; ++c)
            v += spart[((size_t)b * NCHUNK + c) * EMB + e];
        zin[2 * HH + e] = v * v;
    }
    __syncthreads();
    {
        float a = b1[j];
        const float* w = W1 + (size_t)j * (2 * HH + EMB);
        for (int i = 0; i < 2 * HH + EMB; ++i) a += zin[i] * w[i];
        l1[j] = fmaxf(a, 0.f);
    }
    __syncthreads();
    if (j < 64) {
        float a = b2[j];
        const float* w = W2 + (size_t)j * 128;
        for (int i = 0; i < 128; ++i) a += l1[i] * w[i];
        l2[j] = fmaxf(a, 0.f);
    }
    __syncthreads();
    if (j < 23) {
        float a = b3[j];
        const float* w = W3 + (size_t)j * 64;
        for (int i = 0; i < 64; ++i) a += l2[i] * w[i];
        out[b * 23 + j] = a;
    }
}

// ---------------------------------------------------------------------------
extern "C" void kernel_launch(void* const* d_in, const int* in_sizes, int n_in,
                              void* d_out, int out_size, void* d_ws, size_t ws_size,
                              hipStream_t stream) {
    const float* x     = (const float*)d_in[0];
    const float* mask  = (const float*)d_in[2];
    const float* Wih_f = (const float*)d_in[3];
    const float* Whh_f = (const float*)d_in[4];
    const float* bih_f = (const float*)d_in[5];
    const float* bhh_f = (const float*)d_in[6];
    const float* Wih_b = (const float*)d_in[7];
    const float* bih_b = (const float*)d_in[9];
    const float* bhh_b = (const float*)d_in[10];
    const float* W1 = (const float*)d_in[11];
    const float* b1 = (const float*)d_in[12];
    const float* W2 = (const float*)d_in[13];
    const float* b2 = (const float*)d_in[14];
    const float* W3 = (const float*)d_in[15];
    const float* b3 = (const float*)d_in[16];
    float* out = (float*)d_out;

    float* gi    = (float*)d_ws;                          // 64*1024*384 f32
    float* spart = gi + (size_t)BS * SEQ * NG;            // 64*8*300
    float* hf    = spart + (size_t)BS * NCHUNK * EMB;     // 64*128
    float* hb    = hf + BS * HH;                          // 64*128

    gi_gemm<<<dim3(512, 3), dim3(256), 0, stream>>>(x, mask, Wih_f, bih_f, gi);
    col_sum<<<dim3(BS, NCHUNK), dim3(320), 0, stream>>>(x, mask, spart);
    gru_scan<<<dim3(BS), dim3(256), 0, stream>>>(gi, Whh_f, bhh_f, hf);
    gru_bwd<<<dim3(BS), dim3(384), 0, stream>>>(x, mask, Wih_b, bih_b, bhh_b, hb);
    mlp<<<dim3(BS), dim3(128), 0, stream>>>(hf, hb, spart, W1, b1, W2, b2, W3, b3, out);
}